// Round 4
// baseline (139.662 us; speedup 1.0000x reference)
//
#include <hip/hip_runtime.h>
#include <hip/hip_fp16.h>
#include <cstddef>

#define N_ 1024
#define M_ 1024
#define D_ 1024
#define G_ 16
#define DG_ 64

typedef __bf16 bf16x8 __attribute__((ext_vector_type(8)));
typedef _Float16 f16x8 __attribute__((ext_vector_type(8)));
typedef float f32x4 __attribute__((ext_vector_type(4)));

// Fragment-major layout helpers.
__device__ __forceinline__ size_t qkf_idx(int g, int rb, int ks, int lane) {
    return ((((size_t)(g * 64 + rb)) * 2 + ks) * 64 + lane) * 8;
}
__device__ __forceinline__ size_t vf_idx(int g, int ot, int mc, int lane) {
    return ((((size_t)(g * 4 + ot)) * 32 + mc) * 64 + lane) * 8;
}
// AWt layout: [mb(64)][n(1024)][g(16)][m16(16)] — posbias-coalesced.
__device__ __forceinline__ size_t awt_idx(int g, int mb, int n, int quad) {
    return (((size_t)(mb * 1024 + n)) * 16 + g) * 16 + quad * 4;
}

// ---------------------------------------------------------------------------
// R17: GEMM tail was per-CU-BW-bound (measured 6000 cyc/K-step in a 192-block
// tail at 16% occupancy = unhidden 64KB/step/CU). Two fixes, same diagnosis:
//  (a) 128x64 tiles -> 384 GEMM blocks (>=1.5/CU in tail, 48KB/step/block);
//  (b) register-prefetch pipeline: issue step k+1 loads after the LDS-ready
//      barrier, MFMA step k meanwhile (T14 shape). K-order unchanged ->
//      bitwise-identical outputs.
// Grid 1408 = 384 gemm + 1024 posbias (one n per block).
// ---------------------------------------------------------------------------
__global__ __launch_bounds__(256)
void fused_mid3(const float* __restrict__ roi, const float* __restrict__ ref,
                const float* __restrict__ Wq, const float* __restrict__ Wk,
                const float* __restrict__ Wv,
                const float* __restrict__ bq, const float* __restrict__ bk,
                __bf16* __restrict__ Qf, __bf16* __restrict__ Kf,
                __bf16* __restrict__ Vf,
                const float* __restrict__ rois1, const float* __restrict__ rois2,
                const float* __restrict__ Wg, const float* __restrict__ bg,
                __half* __restrict__ AWt)
{
    __shared__ __align__(16) char smem[27648];   // As 18432 + Bs 9216
    const int b = blockIdx.x;
    const int tid = threadIdx.x;
    const int w = tid >> 6, lane = tid & 63;
    const int quad = lane >> 4, l15 = lane & 15;

    if (b < 384) {
        const int z = b >> 7, t6 = b & 127;      // 3 matrices x 128 tiles
        const float* A = (z == 0) ? roi : ref;
        const float* Wf = (z == 0) ? Wq : (z == 1) ? Wk : Wv;
        const int i0 = (t6 >> 4) * 128, j0 = (t6 & 15) * 64;
        const int iw = (w & 1) * 64, jw = (w >> 1) * 32;

        __bf16(*As)[72] = (__bf16(*)[72])smem;             // [128][72]
        __bf16(*Bs)[72] = (__bf16(*)[72])(smem + 18432);   // [64][72]

        f32x4 acc[4][2] = {};

        float4 apf[8];     // A prefetch: 128x64 f32 / 256thr = 8 float4
        float4 bpf4[4];    // B prefetch (z==2 row-major path)
        float  bpfs[16];   // B prefetch (z<2 transpose path)

        // ---- prologue: prefetch k0 = 0 ----
        {
            #pragma unroll
            for (int it = 0; it < 8; ++it) {
                const int idx = tid + 256 * it;
                const int row = idx >> 4, c = idx & 15;
                apf[it] = *(const float4*)&A[(size_t)(i0 + row) * D_ + c * 4];
            }
            if (z < 2) {
                #pragma unroll
                for (int it = 0; it < 4; ++it) {
                    const int idx = tid + 256 * it;
                    const int jl = idx & 63, kc = idx >> 6;
                    const float* src = &Wf[(size_t)(kc * 4) * D_ + j0 + jl];
                    bpfs[it * 4 + 0] = src[0];
                    bpfs[it * 4 + 1] = src[D_];
                    bpfs[it * 4 + 2] = src[2 * D_];
                    bpfs[it * 4 + 3] = src[3 * D_];
                }
            } else {
                #pragma unroll
                for (int it = 0; it < 4; ++it) {
                    const int idx = tid + 256 * it;
                    const int row = idx >> 4, c = idx & 15;
                    bpf4[it] = *(const float4*)&Wf[(size_t)(j0 + row) * D_ + c * 4];
                }
            }
        }

        for (int k0 = 0; k0 < D_; k0 += 64) {
            __syncthreads();   // prev compute done reading LDS
            // ---- write prefetched tile to LDS (f32 -> bf16) ----
            #pragma unroll
            for (int it = 0; it < 8; ++it) {
                const int idx = tid + 256 * it;
                const int row = idx >> 4, c = idx & 15;
                __bf16 p[4] = {(__bf16)apf[it].x, (__bf16)apf[it].y,
                               (__bf16)apf[it].z, (__bf16)apf[it].w};
                *(uint2*)&As[row][c * 4] = *(const uint2*)p;
            }
            if (z < 2) {
                #pragma unroll
                for (int it = 0; it < 4; ++it) {
                    const int idx = tid + 256 * it;
                    const int jl = idx & 63, kc = idx >> 6;
                    __bf16 p[4] = {(__bf16)bpfs[it * 4 + 0], (__bf16)bpfs[it * 4 + 1],
                                   (__bf16)bpfs[it * 4 + 2], (__bf16)bpfs[it * 4 + 3]};
                    *(uint2*)&Bs[jl][kc * 4] = *(const uint2*)p;
                }
            } else {
                #pragma unroll
                for (int it = 0; it < 4; ++it) {
                    const int idx = tid + 256 * it;
                    const int row = idx >> 4, c = idx & 15;
                    __bf16 p[4] = {(__bf16)bpf4[it].x, (__bf16)bpf4[it].y,
                                   (__bf16)bpf4[it].z, (__bf16)bpf4[it].w};
                    *(uint2*)&Bs[row][c * 4] = *(const uint2*)p;
                }
            }
            __syncthreads();   // LDS ready

            // ---- issue NEXT step's loads; latency hides under compute ----
            const int kn = k0 + 64;
            if (kn < D_) {
                #pragma unroll
                for (int it = 0; it < 8; ++it) {
                    const int idx = tid + 256 * it;
                    const int row = idx >> 4, c = idx & 15;
                    apf[it] = *(const float4*)&A[(size_t)(i0 + row) * D_ + kn + c * 4];
                }
                if (z < 2) {
                    #pragma unroll
                    for (int it = 0; it < 4; ++it) {
                        const int idx = tid + 256 * it;
                        const int jl = idx & 63, kc = idx >> 6;
                        const float* src = &Wf[(size_t)(kn + kc * 4) * D_ + j0 + jl];
                        bpfs[it * 4 + 0] = src[0];
                        bpfs[it * 4 + 1] = src[D_];
                        bpfs[it * 4 + 2] = src[2 * D_];
                        bpfs[it * 4 + 3] = src[3 * D_];
                    }
                } else {
                    #pragma unroll
                    for (int it = 0; it < 4; ++it) {
                        const int idx = tid + 256 * it;
                        const int row = idx >> 4, c = idx & 15;
                        bpf4[it] = *(const float4*)&Wf[(size_t)(j0 + row) * D_ + kn + c * 4];
                    }
                }
            }

            // ---- compute current tile ----
            #pragma unroll
            for (int ks = 0; ks < 2; ++ks) {
                bf16x8 af[4], bfr[2];
                #pragma unroll
                for (int t4 = 0; t4 < 4; ++t4)
                    af[t4] = *(const bf16x8*)&As[iw + t4 * 16 + l15][ks * 32 + quad * 8];
                #pragma unroll
                for (int t4 = 0; t4 < 2; ++t4)
                    bfr[t4] = *(const bf16x8*)&Bs[jw + t4 * 16 + l15][ks * 32 + quad * 8];
                #pragma unroll
                for (int ti = 0; ti < 4; ++ti)
                    #pragma unroll
                    for (int tj = 0; tj < 2; ++tj)
                        acc[ti][tj] = __builtin_amdgcn_mfma_f32_16x16x32_bf16(
                            af[ti], bfr[tj], acc[ti][tj], 0, 0, 0);
            }
        }

        if (z < 2) {
            const float* bias = (z == 0) ? bq : bk;
            __bf16* dst = (z == 0) ? Qf : Kf;
            const float scale = (z == 0) ? 0.125f : 1.0f;
            #pragma unroll
            for (int ti = 0; ti < 4; ++ti) {
                const int rb = (i0 + iw + ti * 16) >> 4;
                #pragma unroll
                for (int tj = 0; tj < 2; ++tj) {
                    const int go = j0 + jw + tj * 16 + l15;
                    const int g = go >> 6, ks = (go >> 5) & 1;
                    const int lanef = ((go >> 3) & 3) * 16;
                    const int jf = go & 7;
                    const float bb = bias[go];
                    __bf16* base = dst + qkf_idx(g, rb, ks, 0) + jf;
                    #pragma unroll
                    for (int r = 0; r < 4; ++r)
                        base[(size_t)(lanef + quad * 4 + r) * 8] =
                            (__bf16)((acc[ti][tj][r] + bb) * scale);
                }
            }
        } else {
            #pragma unroll
            for (int ti = 0; ti < 4; ++ti) {
                const int mbase = i0 + iw + ti * 16 + quad * 4;
                const int mc = mbase >> 5, quadv = (mbase >> 3) & 3, jb = mbase & 7;
                #pragma unroll
                for (int tj = 0; tj < 2; ++tj) {
                    const int go = j0 + jw + tj * 16 + l15;
                    const int g = go >> 6, ot = (go >> 4) & 3, o15 = go & 15;
                    __bf16 p[4];
                    #pragma unroll
                    for (int r = 0; r < 4; ++r) p[r] = (__bf16)acc[ti][tj][r];
                    *(uint2*)&Vf[vf_idx(g, ot, mc, quadv * 16 + o15) + jb] =
                        *(const uint2*)p;
                }
            }
        }
        return;
    }

    // ---------------- posbias branch: one n per block, full m sweep --------
    const int n = b - 384;                   // 0..1023

    const float xmin = rois1[n * 4 + 0], ymin = rois1[n * 4 + 1];
    const float xmax = rois1[n * 4 + 2], ymax = rois1[n * 4 + 3];
    const float wn  = xmax - xmin + 1.f, hn  = ymax - ymin + 1.f;
    const float cxn = 0.5f * (xmin + xmax), cyn = 0.5f * (ymin + ymax);
    const float rwn = 1.0f / wn, rhn = 1.0f / hn;
    const float lwn = __logf(wn), lhn = __logf(hn);

    f16x8 wgf[2];
    #pragma unroll
    for (int ks = 0; ks < 2; ++ks) {
        const float* p = &Wg[l15 * 64 + ks * 32 + quad * 8];
        float4 a = *(const float4*)p;
        float4 bb = *(const float4*)(p + 4);
        wgf[ks][0] = (_Float16)a.x; wgf[ks][1] = (_Float16)a.y;
        wgf[ks][2] = (_Float16)a.z; wgf[ks][3] = (_Float16)a.w;
        wgf[ks][4] = (_Float16)bb.x; wgf[ks][5] = (_Float16)bb.y;
        wgf[ks][6] = (_Float16)bb.z; wgf[ks][7] = (_Float16)bb.w;
    }
    const float bgv = bg[l15];

    const float fr8[8] = {100.0f, 42.16965f, 17.782794f, 7.4989421f,
                          3.1622777f, 1.3335214f, 0.56234133f, 0.23713737f};
    const float phase = (quad & 1) ? 1.5707963267948966f : 0.f;

    for (int mq = 0; mq < 4; ++mq) {
        const int m0w = mq * 256 + w * 64;
        #pragma unroll
        for (int ti = 0; ti < 4; ++ti) {
            const int mt0 = m0w + ti * 16;
            const int m = mt0 + l15;
            float4 r2 = *(const float4*)&rois2[m * 4];
            const float wr  = r2.z - r2.x + 1.f, hr  = r2.w - r2.y + 1.f;
            const float cxr = 0.5f * (r2.x + r2.z), cyr = 0.5f * (r2.y + r2.w);

            const float f0 = __logf(fabsf((cxn - cxr) * rwn) + 0.001f);
            const float f1 = __logf(fabsf((cyn - cyr) * rhn) + 0.001f);
            const float f2 = lwn - __logf(wr);
            const float f3 = lhn - __logf(hr);
            const float fa = (quad & 2) ? f1 : f0;
            const float fb = (quad & 2) ? f3 : f2;

            f32x4 acc = {};
            #pragma unroll
            for (int ks = 0; ks < 2; ++ks) {
                const float feat = ks ? fb : fa;
                f16x8 ef;
                #pragma unroll
                for (int j = 0; j < 8; ++j)
                    ef[j] = (_Float16)__sinf(fmaf(feat, fr8[j], phase));
                acc = __builtin_amdgcn_mfma_f32_16x16x32_f16(ef, wgf[ks], acc, 0, 0, 0);
            }

            __half p[4];
            #pragma unroll
            for (int r = 0; r < 4; ++r)
                p[r] = __float2half(fmaxf(acc[r] + bgv, 0.f) + 1e-6f);
            *(uint2*)&AWt[awt_idx(l15, mt0 >> 4, n, quad)] = *(const uint2*)p;
        }
    }
}

// ---------------------------------------------------------------------------
// Wave-autonomous MFMA attention. LDS union v2 (17.7KB). setprio(1) around
// MFMA clusters (catalog T5). Unchanged this round.
// ---------------------------------------------------------------------------
__global__ __launch_bounds__(256)
void attn_mfma(const __bf16* __restrict__ Qf, const __bf16* __restrict__ Kf,
               const __bf16* __restrict__ Vf, const __half* __restrict__ AWt,
               const float* __restrict__ bv, float* __restrict__ out)
{
    __shared__ __align__(16) char smem[17664];

    const int tid = threadIdx.x;
    const int w = tid >> 6, lane = tid & 63;
    const int quad = lane >> 4, l15 = lane & 15;
    const int nb = blockIdx.x, n0 = nb * 16, g = blockIdx.y;

    __bf16(*Psw)[72] = (__bf16(*)[72])(smem + w * 2304);       // [16][72], wave-private
    float(*accb)[64][17] = (float(*)[64][17])smem;             // [4][64][17]
    float(*lsb)[16] = (float(*)[16])(smem + 17408);            // [4][16]

    bf16x8 qf[2];
    qf[0] = *(const bf16x8*)&Qf[qkf_idx(g, nb, 0, lane)];
    qf[1] = *(const bf16x8*)&Qf[qkf_idx(g, nb, 1, lane)];

    f32x4 acc[4] = {};
    float llocal = 0.f;

    #pragma unroll
    for (int t64 = 0; t64 < 4; ++t64) {
        const int mt = w * 4 + t64;

        f32x4 s[4];
        #pragma unroll
        for (int t = 0; t < 4; ++t) {
            bf16x8 ka0 = *(const bf16x8*)&Kf[qkf_idx(g, mt * 4 + t, 0, lane)];
            bf16x8 ka1 = *(const bf16x8*)&Kf[qkf_idx(g, mt * 4 + t, 1, lane)];
            f32x4 z = {};
            __builtin_amdgcn_s_setprio(1);
            z = __builtin_amdgcn_mfma_f32_16x16x32_bf16(ka0, qf[0], z, 0, 0, 0);
            s[t] = __builtin_amdgcn_mfma_f32_16x16x32_bf16(ka1, qf[1], z, 0, 0, 0);
            __builtin_amdgcn_s_setprio(0);
        }

        #pragma unroll
        for (int t = 0; t < 4; ++t) {
            uint2 au = *(const uint2*)&AWt[awt_idx(g, mt * 4 + t, n0 + l15, quad)];
            const __half* a4 = (const __half*)&au;
            __bf16 pk[4];
            #pragma unroll
            for (int r = 0; r < 4; ++r) {
                const float p = __half2float(a4[r]) * __expf(s[t][r]);
                llocal += p;
                pk[r] = (__bf16)p;
            }
            *(uint2*)&Psw[l15][t * 16 + quad * 4] = *(const uint2*)pk;
        }

        #pragma unroll
        for (int mcl = 0; mcl < 2; ++mcl) {
            bf16x8 pbf = *(const bf16x8*)&Psw[l15][mcl * 32 + quad * 8];
            __builtin_amdgcn_s_setprio(1);
            #pragma unroll
            for (int ot = 0; ot < 4; ++ot) {
                bf16x8 va = *(const bf16x8*)&Vf[vf_idx(g, ot, mt * 2 + mcl, lane)];
                acc[ot] = __builtin_amdgcn_mfma_f32_16x16x32_bf16(va, pbf, acc[ot], 0, 0, 0);
            }
            __builtin_amdgcn_s_setprio(0);
        }
    }

    llocal += __shfl_xor(llocal, 16, 64);
    llocal += __shfl_xor(llocal, 32, 64);

    __syncthreads();   // Ps lifetime ends for ALL waves before accb reuses the LDS

    #pragma unroll
    for (int ot = 0; ot < 4; ++ot)
        #pragma unroll
        for (int r = 0; r < 4; ++r)
            accb[w][ot * 16 + quad * 4 + r][l15] = acc[ot][r];
    if (quad == 0) lsb[w][l15] = llocal;
    __syncthreads();

    const float lt = lsb[0][l15] + lsb[1][l15] + lsb[2][l15] + lsb[3][l15];
    const float inv = 1.f / lt;
    #pragma unroll
    for (int r = 0; r < 4; ++r) {
        const int o = w * 16 + quad * 4 + r;
        const int ogl = g * 64 + o;
        const float v = accb[0][o][l15] + accb[1][o][l15] +
                        accb[2][o][l15] + accb[3][o][l15];
        out[(size_t)(n0 + l15) * D_ + ogl] = v * inv + bv[ogl];
    }
}

extern "C" void kernel_launch(void* const* d_in, const int* in_sizes, int n_in,
                              void* d_out, int out_size, void* d_ws, size_t ws_size,
                              hipStream_t stream) {
    const float* roi_feat = (const float*)d_in[0];
    const float* ref_feat = (const float*)d_in[1];
    const float* rois1    = (const float*)d_in[2];
    const float* rois2    = (const float*)d_in[3];
    const float* Wq       = (const float*)d_in[4];
    const float* bq       = (const float*)d_in[5];
    const float* Wk       = (const float*)d_in[6];
    const float* bk       = (const float*)d_in[7];
    const float* Wg       = (const float*)d_in[8];
    const float* bg       = (const float*)d_in[9];
    const float* Wv       = (const float*)d_in[10];
    const float* bv       = (const float*)d_in[11];
    float* out = (float*)d_out;

    // ws (bytes): Qf 0-2M | Kf 2-4M | Vf 4-6M | AWt 6-38M
    char* ws = (char*)d_ws;
    __bf16* Qf  = (__bf16*)(ws + 0);
    __bf16* Kf  = (__bf16*)(ws + (2u << 20));
    __bf16* Vf  = (__bf16*)(ws + (4u << 20));
    __half* AWt = (__half*)(ws + (6u << 20));

    dim3 blk(256);
    fused_mid3<<<dim3(1408), blk, 0, stream>>>(roi_feat, ref_feat, Wq, Wk, Wv,
                                               bq, bk, Qf, Kf, Vf,
                                               rois1, rois2, Wg, bg, AWt);
    attn_mfma<<<dim3(64, 16), blk, 0, stream>>>(Qf, Kf, Vf, AWt, bv, out);
}

// Round 5
// 138.190 us; speedup vs baseline: 1.0107x; 1.0107x over previous
//
#include <hip/hip_runtime.h>
#include <hip/hip_fp16.h>
#include <cstddef>
#include <cstdint>

#define N_ 1024
#define M_ 1024
#define D_ 1024
#define G_ 16
#define DG_ 64

typedef __bf16 bf16x8 __attribute__((ext_vector_type(8)));
typedef _Float16 f16x8 __attribute__((ext_vector_type(8)));
typedef float f32x4 __attribute__((ext_vector_type(4)));

typedef __attribute__((address_space(1))) const void* gas_ptr;
typedef __attribute__((address_space(3))) void* las_ptr;

__device__ __forceinline__ void gl_lds16(const void* g, void* l) {
    __builtin_amdgcn_global_load_lds((gas_ptr)g, (las_ptr)l, 16, 0, 0);
}

// Fragment-major layout helpers.
__device__ __forceinline__ size_t qkf_idx(int g, int rb, int ks, int lane) {
    return ((((size_t)(g * 64 + rb)) * 2 + ks) * 64 + lane) * 8;
}
__device__ __forceinline__ size_t vf_idx(int g, int ot, int mc, int lane) {
    return ((((size_t)(g * 4 + ot)) * 32 + mc) * 64 + lane) * 8;
}
// AWt layout: [mb(64)][n(1024)][g(16)][m16(16)] — posbias-coalesced.
__device__ __forceinline__ size_t awt_idx(int g, int mb, int n, int quad) {
    return (((size_t)(mb * 1024 + n)) * 16 + g) * 16 + quad * 4;
}

// ---------------------------------------------------------------------------
// R18 prep: posbias (1024 blocks, unchanged math) + bf16 casts of roi/ref/Wv
// (192 blocks) + bf16 transposes of Wq/Wk -> [j][k] (512 blocks). Moves ALL
// f32->bf16 work out of the GEMM, halving the GEMM's streamed bytes (the
// R13/16/17-invariant ~288MB fp32 tail was L2/L3-BW-bound at ~7.6 TB/s).
// ---------------------------------------------------------------------------
__global__ __launch_bounds__(256)
void prep_pos(const float* __restrict__ roi, const float* __restrict__ ref,
              const float* __restrict__ Wq, const float* __restrict__ Wk,
              const float* __restrict__ Wv,
              __bf16* __restrict__ roiB, __bf16* __restrict__ refB,
              __bf16* __restrict__ WqT, __bf16* __restrict__ WkT,
              __bf16* __restrict__ WvR,
              const float* __restrict__ rois1, const float* __restrict__ rois2,
              const float* __restrict__ Wg, const float* __restrict__ bg,
              __half* __restrict__ AWt)
{
    __shared__ float tls[64][65];
    const int b = blockIdx.x;
    const int tid = threadIdx.x;
    const int w = tid >> 6, lane = tid & 63;
    const int quad = lane >> 4, l15 = lane & 15;

    if (b < 1024) {
        // ---------------- posbias: one n per block ----------------
        const int n = b;
        const float xmin = rois1[n * 4 + 0], ymin = rois1[n * 4 + 1];
        const float xmax = rois1[n * 4 + 2], ymax = rois1[n * 4 + 3];
        const float wn  = xmax - xmin + 1.f, hn  = ymax - ymin + 1.f;
        const float cxn = 0.5f * (xmin + xmax), cyn = 0.5f * (ymin + ymax);
        const float rwn = 1.0f / wn, rhn = 1.0f / hn;
        const float lwn = __logf(wn), lhn = __logf(hn);

        f16x8 wgf[2];
        #pragma unroll
        for (int ks = 0; ks < 2; ++ks) {
            const float* p = &Wg[l15 * 64 + ks * 32 + quad * 8];
            float4 a = *(const float4*)p;
            float4 bb = *(const float4*)(p + 4);
            wgf[ks][0] = (_Float16)a.x; wgf[ks][1] = (_Float16)a.y;
            wgf[ks][2] = (_Float16)a.z; wgf[ks][3] = (_Float16)a.w;
            wgf[ks][4] = (_Float16)bb.x; wgf[ks][5] = (_Float16)bb.y;
            wgf[ks][6] = (_Float16)bb.z; wgf[ks][7] = (_Float16)bb.w;
        }
        const float bgv = bg[l15];

        const float fr8[8] = {100.0f, 42.16965f, 17.782794f, 7.4989421f,
                              3.1622777f, 1.3335214f, 0.56234133f, 0.23713737f};
        const float phase = (quad & 1) ? 1.5707963267948966f : 0.f;

        for (int mq = 0; mq < 4; ++mq) {
            const int m0w = mq * 256 + w * 64;
            #pragma unroll
            for (int ti = 0; ti < 4; ++ti) {
                const int mt0 = m0w + ti * 16;
                const int m = mt0 + l15;
                float4 r2 = *(const float4*)&rois2[m * 4];
                const float wr  = r2.z - r2.x + 1.f, hr  = r2.w - r2.y + 1.f;
                const float cxr = 0.5f * (r2.x + r2.z), cyr = 0.5f * (r2.y + r2.w);

                const float f0 = __logf(fabsf((cxn - cxr) * rwn) + 0.001f);
                const float f1 = __logf(fabsf((cyn - cyr) * rhn) + 0.001f);
                const float f2 = lwn - __logf(wr);
                const float f3 = lhn - __logf(hr);
                const float fa = (quad & 2) ? f1 : f0;
                const float fb = (quad & 2) ? f3 : f2;

                f32x4 acc = {};
                #pragma unroll
                for (int ks = 0; ks < 2; ++ks) {
                    const float feat = ks ? fb : fa;
                    f16x8 ef;
                    #pragma unroll
                    for (int j = 0; j < 8; ++j)
                        ef[j] = (_Float16)__sinf(fmaf(feat, fr8[j], phase));
                    acc = __builtin_amdgcn_mfma_f32_16x16x32_f16(ef, wgf[ks], acc, 0, 0, 0);
                }

                __half p[4];
                #pragma unroll
                for (int r = 0; r < 4; ++r)
                    p[r] = __float2half(fmaxf(acc[r] + bgv, 0.f) + 1e-6f);
                *(uint2*)&AWt[awt_idx(l15, mt0 >> 4, n, quad)] = *(const uint2*)p;
            }
        }
        return;
    }

    if (b < 1216) {
        // ---------------- flat casts: roi / ref / Wv -> bf16 ----------------
        const int cbk = b - 1024;            // 0..191
        const int mat = cbk >> 6;            // 0=roi 1=ref 2=Wv
        const float* S = (mat == 0) ? roi : (mat == 1) ? ref : Wv;
        __bf16* Dt = (mat == 0) ? roiB : (mat == 1) ? refB : WvR;
        const int base = (cbk & 63) * 16384;
        #pragma unroll
        for (int i = 0; i < 16; ++i) {
            const int e = base + i * 1024 + tid * 4;
            float4 v = *(const float4*)&S[e];
            __bf16 p[4] = {(__bf16)v.x, (__bf16)v.y, (__bf16)v.z, (__bf16)v.w};
            *(uint2*)&Dt[e] = *(const uint2*)p;
        }
        return;
    }

    // ---------------- transpose-cast: Wq/Wk [k][j] -> [j][k] bf16 ----------
    const int tb = b - 1216;                 // 0..511
    const int mat = tb >> 8;                 // 0=Wq 1=Wk
    const float* S = mat ? Wk : Wq;
    __bf16* Dt = mat ? WkT : WqT;
    const int tile = tb & 255;
    const int k0 = (tile >> 4) * 64, j0 = (tile & 15) * 64;

    #pragma unroll
    for (int rr = 0; rr < 4; ++rr) {
        const int row = (tid >> 4) * 4 + rr;
        const int col = (tid & 15) * 4;
        float4 v = *(const float4*)&S[(size_t)(k0 + row) * 1024 + j0 + col];
        tls[row][col + 0] = v.x; tls[row][col + 1] = v.y;
        tls[row][col + 2] = v.z; tls[row][col + 3] = v.w;
    }
    __syncthreads();
    #pragma unroll
    for (int rr = 0; rr < 4; ++rr) {
        const int j = (tid >> 4) * 4 + rr;
        const int kc = (tid & 15) * 4;
        __bf16 p[4] = {(__bf16)tls[kc + 0][j], (__bf16)tls[kc + 1][j],
                       (__bf16)tls[kc + 2][j], (__bf16)tls[kc + 3][j]};
        *(uint2*)&Dt[(size_t)(j0 + j) * 1024 + k0 + kc] = *(const uint2*)p;
    }
}

// ---------------------------------------------------------------------------
// R18 GEMM: bf16 inputs (half the bytes of R17), global_load_lds width=16
// staging (no reg round-trip, no cvt VALU), double-buffered LDS, counted
// vmcnt(6) + raw s_barrier 2-phase loop (T3/T4 minimal form), XOR-swizzled
// via pre-swizzled GLOBAL source + swizzled ds_read (T2/m173: gload_lds dest
// must stay linear). 384 blocks = 3 matrices x (8 i x 16 j) 128x64 tiles.
// LDS 48KB: A 2x16K + B 2x8K.
// ---------------------------------------------------------------------------
__global__ __launch_bounds__(256)
void gemm_qkv2(const __bf16* __restrict__ roiB, const __bf16* __restrict__ refB,
               const __bf16* __restrict__ WqT, const __bf16* __restrict__ WkT,
               const __bf16* __restrict__ WvR,
               const float* __restrict__ bq, const float* __restrict__ bk,
               __bf16* __restrict__ Qf, __bf16* __restrict__ Kf,
               __bf16* __restrict__ Vf)
{
    __shared__ __align__(16) char smem[49152];
    const int b = blockIdx.x;
    const int tid = threadIdx.x;
    const int w = tid >> 6, lane = tid & 63;
    const int quad = lane >> 4, l15 = lane & 15;

    const int z = b >> 7, t6 = b & 127;
    const __bf16* A = (z == 0) ? roiB : refB;
    const __bf16* Bm = (z == 0) ? WqT : (z == 1) ? WkT : WvR;
    const int i0 = (t6 >> 4) * 128, j0 = (t6 & 15) * 64;
    const int iw = (w & 1) * 64, jw = (w >> 1) * 32;

    // Staging source pointers. LDS byte s in a 1KB wave-chunk maps to
    // logical column (s&127)^((row&7)<<4); row&7 == lane>>3, so the
    // per-lane source column offset is constant across chunks and k-steps.
    const int gcolc = (((lane & 7) ^ (lane >> 3)) << 4);
    const char* asrc[4];
    const char* bsrc[2];
    #pragma unroll
    for (int it = 0; it < 4; ++it) {
        const int row = (w * 4 + it) * 8 + (lane >> 3);
        asrc[it] = (const char*)A + (size_t)(i0 + row) * 2048 + gcolc;
    }
    #pragma unroll
    for (int it = 0; it < 2; ++it) {
        const int row = (w * 2 + it) * 8 + (lane >> 3);
        bsrc[it] = (const char*)Bm + (size_t)(j0 + row) * 2048 + gcolc;
    }

    // Swizzled per-lane ds_read offsets (column bits 4-6 XOR'd with l15&7).
    const int swm = (l15 & 7) << 4;
    const int off0 = l15 * 128 + ((quad * 16) ^ swm);
    const int off1 = l15 * 128 + ((64 + quad * 16) ^ swm);

    f32x4 acc[4][2] = {};

    // stage buffer c with k-byte-offset kb
    #define STAGE(c, kb)                                                        \
        do {                                                                    \
            _Pragma("unroll")                                                   \
            for (int it = 0; it < 4; ++it)                                      \
                gl_lds16(asrc[it] + (kb),                                       \
                         smem + (c) * 16384 + (w * 4 + it) * 1024);             \
            _Pragma("unroll")                                                   \
            for (int it = 0; it < 2; ++it)                                      \
                gl_lds16(bsrc[it] + (kb),                                       \
                         smem + 32768 + (c) * 8192 + (w * 2 + it) * 1024);      \
        } while (0)

    STAGE(0, 0);
    int cur = 0;
    for (int t = 0; t < 16; ++t) {
        if (t < 15) {
            STAGE(cur ^ 1, (t + 1) * 128);
            asm volatile("s_waitcnt vmcnt(6)" ::: "memory");  // cur's 6 landed
        } else {
            asm volatile("s_waitcnt vmcnt(0)" ::: "memory");
        }
        __builtin_amdgcn_s_barrier();     // all waves' cur-stage visible

        const char* Ab = smem + cur * 16384;
        const char* Bb = smem + 32768 + cur * 8192;
        #pragma unroll
        for (int ks = 0; ks < 2; ++ks) {
            const int offk = ks ? off1 : off0;
            bf16x8 af[4], bfr[2];
            #pragma unroll
            for (int t4 = 0; t4 < 4; ++t4)
                af[t4] = *(const bf16x8*)(Ab + (iw + t4 * 16) * 128 + offk);
            #pragma unroll
            for (int t4 = 0; t4 < 2; ++t4)
                bfr[t4] = *(const bf16x8*)(Bb + (jw + t4 * 16) * 128 + offk);
            #pragma unroll
            for (int ti = 0; ti < 4; ++ti)
                #pragma unroll
                for (int tj = 0; tj < 2; ++tj)
                    acc[ti][tj] = __builtin_amdgcn_mfma_f32_16x16x32_bf16(
                        af[ti], bfr[tj], acc[ti][tj], 0, 0, 0);
        }
        asm volatile("s_waitcnt lgkmcnt(0)" ::: "memory");  // my ds_reads done
        __builtin_amdgcn_s_barrier();     // safe to overwrite cur next iter
        cur ^= 1;
    }
    #undef STAGE

    if (z < 2) {
        const float* bias = (z == 0) ? bq : bk;
        __bf16* dst = (z == 0) ? Qf : Kf;
        const float scale = (z == 0) ? 0.125f : 1.0f;
        #pragma unroll
        for (int ti = 0; ti < 4; ++ti) {
            const int rb = (i0 + iw + ti * 16) >> 4;
            #pragma unroll
            for (int tj = 0; tj < 2; ++tj) {
                const int go = j0 + jw + tj * 16 + l15;
                const int g = go >> 6, ks = (go >> 5) & 1;
                const int lanef = ((go >> 3) & 3) * 16;
                const int jf = go & 7;
                const float bb = bias[go];
                __bf16* base = dst + qkf_idx(g, rb, ks, 0) + jf;
                #pragma unroll
                for (int r = 0; r < 4; ++r)
                    base[(size_t)(lanef + quad * 4 + r) * 8] =
                        (__bf16)((acc[ti][tj][r] + bb) * scale);
            }
        }
    } else {
        #pragma unroll
        for (int ti = 0; ti < 4; ++ti) {
            const int mbase = i0 + iw + ti * 16 + quad * 4;
            const int mc = mbase >> 5, quadv = (mbase >> 3) & 3, jb = mbase & 7;
            #pragma unroll
            for (int tj = 0; tj < 2; ++tj) {
                const int go = j0 + jw + tj * 16 + l15;
                const int g = go >> 6, ot = (go >> 4) & 3, o15 = go & 15;
                __bf16 p[4];
                #pragma unroll
                for (int r = 0; r < 4; ++r) p[r] = (__bf16)acc[ti][tj][r];
                *(uint2*)&Vf[vf_idx(g, ot, mc, quadv * 16 + o15) + jb] =
                    *(const uint2*)p;
            }
        }
    }
}

// ---------------------------------------------------------------------------
// Wave-autonomous MFMA attention. LDS union v2 (17.7KB). setprio(1) around
// MFMA clusters (catalog T5). Unchanged this round.
// ---------------------------------------------------------------------------
__global__ __launch_bounds__(256)
void attn_mfma(const __bf16* __restrict__ Qf, const __bf16* __restrict__ Kf,
               const __bf16* __restrict__ Vf, const __half* __restrict__ AWt,
               const float* __restrict__ bv, float* __restrict__ out)
{
    __shared__ __align__(16) char smem[17664];

    const int tid = threadIdx.x;
    const int w = tid >> 6, lane = tid & 63;
    const int quad = lane >> 4, l15 = lane & 15;
    const int nb = blockIdx.x, n0 = nb * 16, g = blockIdx.y;

    __bf16(*Psw)[72] = (__bf16(*)[72])(smem + w * 2304);       // [16][72], wave-private
    float(*accb)[64][17] = (float(*)[64][17])smem;             // [4][64][17]
    float(*lsb)[16] = (float(*)[16])(smem + 17408);            // [4][16]

    bf16x8 qf[2];
    qf[0] = *(const bf16x8*)&Qf[qkf_idx(g, nb, 0, lane)];
    qf[1] = *(const bf16x8*)&Qf[qkf_idx(g, nb, 1, lane)];

    f32x4 acc[4] = {};
    float llocal = 0.f;

    #pragma unroll
    for (int t64 = 0; t64 < 4; ++t64) {
        const int mt = w * 4 + t64;

        f32x4 s[4];
        #pragma unroll
        for (int t = 0; t < 4; ++t) {
            bf16x8 ka0 = *(const bf16x8*)&Kf[qkf_idx(g, mt * 4 + t, 0, lane)];
            bf16x8 ka1 = *(const bf16x8*)&Kf[qkf_idx(g, mt * 4 + t, 1, lane)];
            f32x4 z = {};
            __builtin_amdgcn_s_setprio(1);
            z = __builtin_amdgcn_mfma_f32_16x16x32_bf16(ka0, qf[0], z, 0, 0, 0);
            s[t] = __builtin_amdgcn_mfma_f32_16x16x32_bf16(ka1, qf[1], z, 0, 0, 0);
            __builtin_amdgcn_s_setprio(0);
        }

        #pragma unroll
        for (int t = 0; t < 4; ++t) {
            uint2 au = *(const uint2*)&AWt[awt_idx(g, mt * 4 + t, n0 + l15, quad)];
            const __half* a4 = (const __half*)&au;
            __bf16 pk[4];
            #pragma unroll
            for (int r = 0; r < 4; ++r) {
                const float p = __half2float(a4[r]) * __expf(s[t][r]);
                llocal += p;
                pk[r] = (__bf16)p;
            }
            *(uint2*)&Psw[l15][t * 16 + quad * 4] = *(const uint2*)pk;
        }

        #pragma unroll
        for (int mcl = 0; mcl < 2; ++mcl) {
            bf16x8 pbf = *(const bf16x8*)&Psw[l15][mcl * 32 + quad * 8];
            __builtin_amdgcn_s_setprio(1);
            #pragma unroll
            for (int ot = 0; ot < 4; ++ot) {
                bf16x8 va = *(const bf16x8*)&Vf[vf_idx(g, ot, mt * 2 + mcl, lane)];
                acc[ot] = __builtin_amdgcn_mfma_f32_16x16x32_bf16(va, pbf, acc[ot], 0, 0, 0);
            }
            __builtin_amdgcn_s_setprio(0);
        }
    }

    llocal += __shfl_xor(llocal, 16, 64);
    llocal += __shfl_xor(llocal, 32, 64);

    __syncthreads();   // Ps lifetime ends for ALL waves before accb reuses the LDS

    #pragma unroll
    for (int ot = 0; ot < 4; ++ot)
        #pragma unroll
        for (int r = 0; r < 4; ++r)
            accb[w][ot * 16 + quad * 4 + r][l15] = acc[ot][r];
    if (quad == 0) lsb[w][l15] = llocal;
    __syncthreads();

    const float lt = lsb[0][l15] + lsb[1][l15] + lsb[2][l15] + lsb[3][l15];
    const float inv = 1.f / lt;
    #pragma unroll
    for (int r = 0; r < 4; ++r) {
        const int o = w * 16 + quad * 4 + r;
        const int ogl = g * 64 + o;
        const float v = accb[0][o][l15] + accb[1][o][l15] +
                        accb[2][o][l15] + accb[3][o][l15];
        out[(size_t)(n0 + l15) * D_ + ogl] = v * inv + bv[ogl];
    }
}

extern "C" void kernel_launch(void* const* d_in, const int* in_sizes, int n_in,
                              void* d_out, int out_size, void* d_ws, size_t ws_size,
                              hipStream_t stream) {
    const float* roi_feat = (const float*)d_in[0];
    const float* ref_feat = (const float*)d_in[1];
    const float* rois1    = (const float*)d_in[2];
    const float* rois2    = (const float*)d_in[3];
    const float* Wq       = (const float*)d_in[4];
    const float* bq       = (const float*)d_in[5];
    const float* Wk       = (const float*)d_in[6];
    const float* bk       = (const float*)d_in[7];
    const float* Wg       = (const float*)d_in[8];
    const float* bg       = (const float*)d_in[9];
    const float* Wv       = (const float*)d_in[10];
    const float* bv       = (const float*)d_in[11];
    float* out = (float*)d_out;

    // ws (bytes): Qf 0-2M | Kf 2-4M | Vf 4-6M | AWt 6M-39.6M |
    //             roiB 40M | refB 42M | WqT 44M | WkT 46M | WvR 48M
    char* ws = (char*)d_ws;
    __bf16* Qf   = (__bf16*)(ws + 0);
    __bf16* Kf   = (__bf16*)(ws + (2u << 20));
    __bf16* Vf   = (__bf16*)(ws + (4u << 20));
    __half* AWt  = (__half*)(ws + (6u << 20));
    __bf16* roiB = (__bf16*)(ws + (40u << 20));
    __bf16* refB = (__bf16*)(ws + (42u << 20));
    __bf16* WqT  = (__bf16*)(ws + (44u << 20));
    __bf16* WkT  = (__bf16*)(ws + (46u << 20));
    __bf16* WvR  = (__bf16*)(ws + (48u << 20));

    dim3 blk(256);
    prep_pos<<<dim3(1728), blk, 0, stream>>>(roi_feat, ref_feat, Wq, Wk, Wv,
                                             roiB, refB, WqT, WkT, WvR,
                                             rois1, rois2, Wg, bg, AWt);
    gemm_qkv2<<<dim3(384), blk, 0, stream>>>(roiB, refB, WqT, WkT, WvR,
                                             bq, bk, Qf, Kf, Vf);
    attn_mfma<<<dim3(64, 16), blk, 0, stream>>>(Qf, Kf, Vf, AWt, bv, out);
}